// Round 7
// baseline (410383.008 us; speedup 1.0000x reference)
//
#include <hip/hip_runtime.h>
#include <cstdint>
#include <cstddef>

#define SEQ 512
#define BATCH 256
#define SD 1024
#define OD 256
#define NG 16          // groups (batch tiles)
#define GB 16          // batches per group
#define NW 16          // workgroups per group

// 8 bf16 values packed as shorts (4 VGPRs) -- guide-verified MFMA frag type
typedef short  bf8   __attribute__((ext_vector_type(8)));
typedef float  f32x4 __attribute__((ext_vector_type(4)));
typedef unsigned int u32x4 __attribute__((ext_vector_type(4)));

union BF16x8 { unsigned long long q[2]; u32x4 u; bf8 v; };

template <bool V> struct BoolC { static constexpr bool value = V; };

__device__ __forceinline__ unsigned short f2bf(float f) {
    unsigned u = __float_as_uint(f);
    u += 0x7FFFu + ((u >> 16) & 1u);      // round-to-nearest-even
    return (unsigned short)(u >> 16);
}

__device__ __forceinline__ float fast_tanh(float v) {
    float e = __expf(2.0f * v);
    return 1.0f - 2.0f / (e + 1.0f);
}

// agent-scope access: coherence point beyond L2, correct for ANY placement.
__device__ __forceinline__ bf8 t_load16_agent(const unsigned short* p) {
    BF16x8 u;
    unsigned long long* q = (unsigned long long*)p;
    u.q[0] = __hip_atomic_load(q,     __ATOMIC_RELAXED, __HIP_MEMORY_SCOPE_AGENT);
    u.q[1] = __hip_atomic_load(q + 1, __ATOMIC_RELAXED, __HIP_MEMORY_SCOPE_AGENT);
    return u.v;
}

// Persistent kernel: 256 wgs = 16 groups x 16 wgs; group handles 16 batches;
// wg owns 64 state-cols of w_r (128 VGPRs of bf16 frags) and 16 out-cols of
// w_o.
//
// Round-6 (verified on HW): after a one-time agent-scope exchange of
// HW_REG_XCC_ID, groups whose 16 members share an XCD run the t-buffer DATA
// path L2-locally (plain stores -> write-through L1 -> XCD L2; sc0 loads ->
// L1-bypass, L2-serve). Verified by FETCH 219->89MB, WRITE 398->137MB,
// 1850->1455us, pass.
//
// Round-7 (this version): the BARRIER also goes L2-local for verified
// groups: workgroup-scope global_atomic_add (no sc1 -> executes in the
// local XCD L2), volatile plain flag store (lands in L2) + agent-scope
// mirror, sc0 flag poll (the round-6-proven L1-bypass primitive) with a
// bounded-spin fallback to the agent mirror -> cannot hang, worst case is
// slow progress. Placement-check failure -> byte-identical round-0
// agent-scope path everywhere.
__global__ void __launch_bounds__(256, 1)
rnn_persistent(const float* __restrict__ x,
               const float* __restrict__ h_init,
               const float* __restrict__ w_r,
               const float* __restrict__ b_r,
               const float* __restrict__ w_o,
               const float* __restrict__ b_o,
               float* __restrict__ out,
               unsigned char* __restrict__ ws)
{
    const int wg   = blockIdx.x;
    const int g    = wg & 15;      // group; members share blockIdx mod 8 -> same XCD (verified below)
    const int wi   = wg >> 4;      // 0..15 within group
    const int tid  = threadIdx.x;
    const int lane = tid & 63;
    const int wid  = tid >> 6;     // wave 0..3
    const int l15  = lane & 15;
    const int lq   = lane >> 4;    // k-quad 0..3

    // per-group control block, 256B each, all within the zeroed first 4KB:
    //  +0 main counter | +64 main flag | +68 agent-mirror flag
    //  +128 startup counter | +132 startup flag | +136.. xcc[16]
    unsigned char* gctl = ws + (size_t)g * 256;
    unsigned* cnt   = (unsigned*)(gctl + 0);
    unsigned* flag  = (unsigned*)(gctl + 64);
    unsigned* flagA = (unsigned*)(gctl + 68);
    unsigned* scnt  = (unsigned*)(gctl + 128);
    unsigned* sflag = (unsigned*)(gctl + 132);
    unsigned* xarr  = (unsigned*)(gctl + 136);
    unsigned short* tbase = (unsigned short*)(ws + 4096);  // 3 x [256][1024] bf16

    const int batch0 = g * GB;     // group's batch rows
    const int s0 = wi * 64;        // wg's state cols
    const int o0 = wi * 16;        // wg's output cols
    const int k0 = wid * 256;      // wave's K slice

    __shared__ float red1[4][4][4][68];  // [wave][coltile][reg][lane] (+4 pad: bank spread)
    __shared__ float red2[4][4][68];     // [wave][reg][lane]
    __shared__ unsigned sx[16];

    // ---- preload w_r slice as B fragments in registers (128 VGPRs) ----
    bf8 B1[4][8];
#pragma unroll
    for (int ct = 0; ct < 4; ++ct) {
#pragma unroll
        for (int kk = 0; kk < 8; ++kk) {
            const float* p = w_r + (size_t)(s0 + ct * 16 + l15) * SD + (k0 + kk * 32 + lq * 8);
            bf8 f;
#pragma unroll
            for (int j = 0; j < 8; ++j) f[j] = (short)f2bf(p[j]);
            B1[ct][kk] = f;
        }
    }
    // ---- w_o slice: 16 rows -> full N=16 tile ----
    bf8 B2[8];
#pragma unroll
    for (int kk = 0; kk < 8; ++kk) {
        const float* p = w_o + (size_t)(o0 + l15) * SD + (k0 + kk * 32 + lq * 8);
        bf8 f;
#pragma unroll
        for (int j = 0; j < 8; ++j) f[j] = (short)f2bf(p[j]);
        B2[kk] = f;
    }

    // ---- per-thread h ownership: 4 consecutive states of one batch row ----
    const int hr = tid >> 4;            // batch-local row 0..15
    const int hc = (tid & 15) * 4;      // state-local col base 0..60
    float4 br4  = *(const float4*)(b_r + s0 + hc);
    float4 hreg = *(const float4*)(h_init + (size_t)(batch0 + hr) * SD + s0 + hc);

    const int ct1 = hc >> 4;
    const int rg1 = hr & 3;
    const int ln1 = (hr >> 2) * 16 + (hc & 15);

    const int er  = tid >> 4;           // err element (row, col): one per thread
    const int ec  = tid & 15;
    const int rg2 = er & 3;
    const int ln2 = (er >> 2) * 16 + ec;
    const float bo = b_o[o0 + ec];

    const size_t t_off = (size_t)(batch0 + hr) * SD + s0 + hc;

    // ---- one-time XCD placement check (agent-scope, always correct) ----
    unsigned xcc = 0;
    asm volatile("s_getreg_b32 %0, hwreg(HW_REG_XCC_ID)" : "=s"(xcc));
    if (tid == 0)
        __hip_atomic_store(xarr + wi, xcc + 1u, __ATOMIC_RELAXED, __HIP_MEMORY_SCOPE_AGENT);
    __syncthreads();   // drains the xcc store (vmcnt) before the arrival add
    if (tid == 0) {
        unsigned old = __hip_atomic_fetch_add(scnt, 1u, __ATOMIC_RELAXED, __HIP_MEMORY_SCOPE_AGENT);
        if (old == 15u)
            __hip_atomic_store(sflag, 1u, __ATOMIC_RELAXED, __HIP_MEMORY_SCOPE_AGENT);
        while (__hip_atomic_load(sflag, __ATOMIC_RELAXED, __HIP_MEMORY_SCOPE_AGENT) < 1u)
            __builtin_amdgcn_s_sleep(1);
    }
    __syncthreads();
    if (tid < 16)
        sx[tid] = __hip_atomic_load(xarr + tid, __ATOMIC_RELAXED, __HIP_MEMORY_SCOPE_AGENT);
    __syncthreads();
    bool fastpath = true;
    for (int j = 1; j < 16; ++j) fastpath &= (sx[j] == sx[0]);

    // ================= main body, specialized on FAST =================
    auto body = [&](auto FC) {
        constexpr bool FAST = decltype(FC)::value;

        auto t_store = [&](unsigned short* p, float a, float b, float c, float d) {
            unsigned long long v = (unsigned long long)f2bf(a)
                                 | ((unsigned long long)f2bf(b) << 16)
                                 | ((unsigned long long)f2bf(c) << 32)
                                 | ((unsigned long long)f2bf(d) << 48);
            if constexpr (FAST) {             // write-through L1 -> lands in XCD L2
                *(unsigned long long*)p = v;
            } else {
                __hip_atomic_store((unsigned long long*)p, v, __ATOMIC_RELAXED, __HIP_MEMORY_SCOPE_AGENT);
            }
        };

        // load 8 A fragments; FAST: sc0 loads (L1-bypass, L2-serve; round-6 verified)
        auto loadA = [&](bf8 (&A)[8], const unsigned short* ap) {
            if constexpr (FAST) {
                u32x4 r[8];
#pragma unroll
                for (int kk = 0; kk < 8; ++kk)
                    asm volatile("global_load_dwordx4 %0, %1, off sc0"
                                 : "=v"(r[kk]) : "v"((const void*)(ap + kk * 32)));
                asm volatile("s_waitcnt vmcnt(0)" ::: "memory");
                __builtin_amdgcn_sched_barrier(0);   // rule #18: keep MFMAs after the wait
#pragma unroll
                for (int kk = 0; kk < 8; ++kk) {
                    BF16x8 u; u.u = r[kk]; A[kk] = u.v;
                }
            } else {
#pragma unroll
                for (int kk = 0; kk < 8; ++kk) A[kk] = t_load16_agent(ap + kk * 32);
            }
        };

        // ---- barrier: L2-local for verified groups, agent-scope otherwise ----
        auto arrive = [&](unsigned phase) {
            __syncthreads();  // drains vmcnt: all t-stores at L2 (FAST) / coherence pt (slow)
            if (tid == 0) {
                unsigned old;
                if constexpr (FAST)   // no sc1 -> atomic executes in the local XCD L2
                    old = __hip_atomic_fetch_add(cnt, 1u, __ATOMIC_RELAXED, __HIP_MEMORY_SCOPE_WORKGROUP);
                else
                    old = __hip_atomic_fetch_add(cnt, 1u, __ATOMIC_RELAXED, __HIP_MEMORY_SCOPE_AGENT);
                if (old == phase * (unsigned)NW + (NW - 1)) {
                    if constexpr (FAST) {
                        *(volatile unsigned*)flag = phase + 1u;  // plain -> L2 (sc0 pollers see it)
                        __hip_atomic_store(flagA, phase + 1u, __ATOMIC_RELAXED, __HIP_MEMORY_SCOPE_AGENT); // hang-proof mirror
                    } else {
                        __hip_atomic_store(flag, phase + 1u, __ATOMIC_RELAXED, __HIP_MEMORY_SCOPE_AGENT);
                    }
                }
            }
        };
        auto wait = [&](unsigned phase) {
            if (tid == 0) {
                if constexpr (FAST) {
                    unsigned v; int spins = 0;
                    for (;;) {
                        asm volatile("global_load_dword %0, %1, off sc0\n\ts_waitcnt vmcnt(0)"
                                     : "=v"(v) : "v"((const void*)flag) : "memory");
                        if (v >= phase + 1u) break;
                        if (++spins > 8192) {   // safety net: read agent mirror, throttled
                            v = __hip_atomic_load(flagA, __ATOMIC_RELAXED, __HIP_MEMORY_SCOPE_AGENT);
                            if (v >= phase + 1u) break;
                            __builtin_amdgcn_s_sleep(1);
                            spins = 8192;       // stay in fallback cadence
                        }
                    }
                } else {
                    while (__hip_atomic_load(flag, __ATOMIC_RELAXED, __HIP_MEMORY_SCOPE_AGENT) < phase + 1u)
                        __builtin_amdgcn_s_sleep(1);
                }
            }
            __syncthreads();
        };

        bf8 A[8];  // A fragments of current t tile (reused by gemm1 AND gemm2)

        auto gemm2 = [&](int tstep) {
            size_t oidx = (size_t)tstep * (BATCH * OD) + (size_t)(batch0 + er) * OD + o0 + ec;
            float xv = x[oidx];                       // issue early, overlaps MFMA
            f32x4 c = {0.f, 0.f, 0.f, 0.f};
#pragma unroll
            for (int kk = 0; kk < 8; ++kk)
                c = __builtin_amdgcn_mfma_f32_16x16x32_bf16(A[kk], B2[kk], c, 0, 0, 0);
#pragma unroll
            for (int q = 0; q < 4; ++q) red2[wid][q][lane] = c[q];
            __syncthreads();
            float sum = red2[0][rg2][ln2] + red2[1][rg2][ln2]
                      + red2[2][rg2][ln2] + red2[3][rg2][ln2];
            out[oidx] = sum + bo - xv;
        };

        // ---- t0 = tanh(h_init) into buffer 0 ----
        t_store(tbase + t_off, fast_tanh(hreg.x), fast_tanh(hreg.y),
                               fast_tanh(hreg.z), fast_tanh(hreg.w));
        arrive(0);
        wait(0);

        for (int i = 0; i < SEQ; ++i) {
            const unsigned short* tb = tbase + (size_t)(i % 3) * (BATCH * SD);
            unsigned short* tn = tbase + (size_t)((i + 1) % 3) * (BATCH * SD);

            // ---- A fragments: 16 rows x wave's K slice ----
            const unsigned short* ap = tb + (size_t)(batch0 + l15) * SD + k0 + lq * 8;
            loadA(A, ap);

            // ---- recurrent GEMM: C[16x64] per wave over its K slice ----
            f32x4 acc0 = {0.f,0.f,0.f,0.f}, acc1 = {0.f,0.f,0.f,0.f};
            f32x4 acc2 = {0.f,0.f,0.f,0.f}, acc3 = {0.f,0.f,0.f,0.f};
#pragma unroll
            for (int kk = 0; kk < 8; ++kk) {
                acc0 = __builtin_amdgcn_mfma_f32_16x16x32_bf16(A[kk], B1[0][kk], acc0, 0, 0, 0);
                acc1 = __builtin_amdgcn_mfma_f32_16x16x32_bf16(A[kk], B1[1][kk], acc1, 0, 0, 0);
                acc2 = __builtin_amdgcn_mfma_f32_16x16x32_bf16(A[kk], B1[2][kk], acc2, 0, 0, 0);
                acc3 = __builtin_amdgcn_mfma_f32_16x16x32_bf16(A[kk], B1[3][kk], acc3, 0, 0, 0);
            }
#pragma unroll
            for (int q = 0; q < 4; ++q) {
                red1[wid][0][q][lane] = acc0[q];
                red1[wid][1][q][lane] = acc1[q];
                red1[wid][2][q][lane] = acc2[q];
                red1[wid][3][q][lane] = acc3[q];
            }
            __syncthreads();

            // ---- K-reduction across 4 waves + leaky h update + tanh + publish ----
            float4 p0 = *(const float4*)&red1[0][ct1][rg1][ln1];
            float4 p1 = *(const float4*)&red1[1][ct1][rg1][ln1];
            float4 p2 = *(const float4*)&red1[2][ct1][rg1][ln1];
            float4 p3 = *(const float4*)&red1[3][ct1][rg1][ln1];
            hreg.x = 0.9f * hreg.x + 0.1f * (p0.x + p1.x + p2.x + p3.x + br4.x);
            hreg.y = 0.9f * hreg.y + 0.1f * (p0.y + p1.y + p2.y + p3.y + br4.y);
            hreg.z = 0.9f * hreg.z + 0.1f * (p0.z + p1.z + p2.z + p3.z + br4.z);
            hreg.w = 0.9f * hreg.w + 0.1f * (p0.w + p1.w + p2.w + p3.w + br4.w);
            t_store(tn + t_off, fast_tanh(hreg.x), fast_tanh(hreg.y),
                                fast_tanh(hreg.z), fast_tanh(hreg.w));

            arrive(i + 1);

            // ---- off-critical-path: err_{i-1} reuses this step's A frags ----
            if (i >= 1) gemm2(i - 1);

            wait(i + 1);
        }

        // ---- epilogue: err_{511} from t_512 (published; last wait ordered it) ----
        {
            const unsigned short* tb = tbase + (size_t)(SEQ % 3) * (BATCH * SD);
            const unsigned short* ap = tb + (size_t)(batch0 + l15) * SD + k0 + lq * 8;
            loadA(A, ap);
            gemm2(SEQ - 1);
        }
    };

    if (fastpath) {
        body(BoolC<true>{});
    } else {
        body(BoolC<false>{});
    }
}

extern "C" void kernel_launch(void* const* d_in, const int* in_sizes, int n_in,
                              void* d_out, int out_size, void* d_ws, size_t ws_size,
                              hipStream_t stream)
{
    const float* x      = (const float*)d_in[0];
    const float* h_init = (const float*)d_in[1];
    const float* w_r    = (const float*)d_in[2];
    const float* b_r    = (const float*)d_in[3];
    const float* w_o    = (const float*)d_in[4];
    const float* b_o    = (const float*)d_in[5];
    float* out = (float*)d_out;

    // ws layout: [0,4096) per-group control blocks (256B each), [4096, +3*512K) t triple buffer
    hipMemsetAsync(d_ws, 0, 4096, stream);
    rnn_persistent<<<dim3(256), dim3(256), 0, stream>>>(
        x, h_init, w_r, b_r, w_o, b_o, out, (unsigned char*)d_ws);
}

// Round 8
// 1428.327 us; speedup vs baseline: 287.3174x; 287.3174x over previous
//
#include <hip/hip_runtime.h>
#include <cstdint>
#include <cstddef>

#define SEQ 512
#define BATCH 256
#define SD 1024
#define OD 256
#define NG 16          // groups (batch tiles)
#define GB 16          // batches per group
#define NW 16          // workgroups per group

// 8 bf16 values packed as shorts (4 VGPRs) -- guide-verified MFMA frag type
typedef short  bf8   __attribute__((ext_vector_type(8)));
typedef float  f32x4 __attribute__((ext_vector_type(4)));
typedef unsigned int u32x4 __attribute__((ext_vector_type(4)));

union BF16x8 { unsigned long long q[2]; u32x4 u; bf8 v; };

template <bool V> struct BoolC { static constexpr bool value = V; };

__device__ __forceinline__ unsigned short f2bf(float f) {
    unsigned u = __float_as_uint(f);
    u += 0x7FFFu + ((u >> 16) & 1u);      // round-to-nearest-even
    return (unsigned short)(u >> 16);
}

__device__ __forceinline__ float fast_tanh(float v) {
    float e = __expf(2.0f * v);
    return 1.0f - 2.0f / (e + 1.0f);
}

// agent-scope access: coherence point beyond L2, correct for ANY placement.
__device__ __forceinline__ bf8 t_load16_agent(const unsigned short* p) {
    BF16x8 u;
    unsigned long long* q = (unsigned long long*)p;
    u.q[0] = __hip_atomic_load(q,     __ATOMIC_RELAXED, __HIP_MEMORY_SCOPE_AGENT);
    u.q[1] = __hip_atomic_load(q + 1, __ATOMIC_RELAXED, __HIP_MEMORY_SCOPE_AGENT);
    return u.v;
}

// Persistent kernel: 256 wgs = 16 groups x 16 wgs; group handles 16 batches;
// wg owns 64 state-cols of w_r (128 VGPRs of bf16 frags) and 16 out-cols of
// w_o.
//
// HW-verified facts driving this design:
//  (r6) With all 16 group members on one XCD (checked via HW_REG_XCC_ID),
//       the t data path runs L2-local: plain stores (write-through L1 ->
//       XCD L2) + sc0 loads. FETCH 219->89MB, WRITE 398->137MB, 1850->1455us.
//  (r7) sc0 polling of a HOT line does NOT observe remote plain stores
//       (L1-resident lines are served stale). Data loads work because t
//       lines are naturally cold in L1 (32KB streams/step through 32KB L1).
//       => flags must be agent-scope atomics, always.
//
// Round-8 barrier: 16 per-WG flags in one 64B line, agent scope.
//  publish: __syncthreads (drains all waves' t-stores into L2) then ONE
//           agent-scope flag store by tid0 -- no central fetch_add RMW hop.
//  wait:    tid0 polls all 16 flags (16 pipelined agent loads, one latency),
//           s_sleep(1)-throttled, single poller per WG (round-0 cadence,
//           no round-1 poll flood). Monotone flags, unconditional publish
//           => deadlock-impossible.
// Triple-buffer safety: WG writes t_{i+1} (overwriting t_{i-2}'s buffer)
// only after wait(all flags >= i+1); flag i is published by each WG at the
// END of its step i-2, i.e. after its loadA(t_{i-2}) completed.
__global__ void __launch_bounds__(256, 1)
rnn_persistent(const float* __restrict__ x,
               const float* __restrict__ h_init,
               const float* __restrict__ w_r,
               const float* __restrict__ b_r,
               const float* __restrict__ w_o,
               const float* __restrict__ b_o,
               float* __restrict__ out,
               unsigned char* __restrict__ ws)
{
    const int wg   = blockIdx.x;
    const int g    = wg & 15;      // group; members share blockIdx mod 8 -> same XCD (verified below)
    const int wi   = wg >> 4;      // 0..15 within group
    const int tid  = threadIdx.x;
    const int lane = tid & 63;
    const int wid  = tid >> 6;     // wave 0..3
    const int l15  = lane & 15;
    const int lq   = lane >> 4;    // k-quad 0..3

    // per-group control block, 256B each, all within the zeroed first 4KB:
    //  +0..63 flags[16] (one 64B line) | +128 startup counter | +132 startup flag
    //  +136.. xcc[16]
    unsigned char* gctl = ws + (size_t)g * 256;
    unsigned* flags = (unsigned*)(gctl + 0);
    unsigned* scnt  = (unsigned*)(gctl + 128);
    unsigned* sflag = (unsigned*)(gctl + 132);
    unsigned* xarr  = (unsigned*)(gctl + 136);
    unsigned* const myflag = flags + wi;
    unsigned short* tbase = (unsigned short*)(ws + 4096);  // 3 x [256][1024] bf16

    const int batch0 = g * GB;     // group's batch rows
    const int s0 = wi * 64;        // wg's state cols
    const int o0 = wi * 16;        // wg's output cols
    const int k0 = wid * 256;      // wave's K slice

    __shared__ float red1[4][4][4][68];  // [wave][coltile][reg][lane] (+4 pad: bank spread)
    __shared__ float red2[4][4][68];     // [wave][reg][lane]
    __shared__ unsigned sx[16];

    // ---- preload w_r slice as B fragments in registers (128 VGPRs) ----
    bf8 B1[4][8];
#pragma unroll
    for (int ct = 0; ct < 4; ++ct) {
#pragma unroll
        for (int kk = 0; kk < 8; ++kk) {
            const float* p = w_r + (size_t)(s0 + ct * 16 + l15) * SD + (k0 + kk * 32 + lq * 8);
            bf8 f;
#pragma unroll
            for (int j = 0; j < 8; ++j) f[j] = (short)f2bf(p[j]);
            B1[ct][kk] = f;
        }
    }
    // ---- w_o slice: 16 rows -> full N=16 tile ----
    bf8 B2[8];
#pragma unroll
    for (int kk = 0; kk < 8; ++kk) {
        const float* p = w_o + (size_t)(o0 + l15) * SD + (k0 + kk * 32 + lq * 8);
        bf8 f;
#pragma unroll
        for (int j = 0; j < 8; ++j) f[j] = (short)f2bf(p[j]);
        B2[kk] = f;
    }

    // ---- per-thread h ownership: 4 consecutive states of one batch row ----
    const int hr = tid >> 4;            // batch-local row 0..15
    const int hc = (tid & 15) * 4;      // state-local col base 0..60
    float4 br4  = *(const float4*)(b_r + s0 + hc);
    float4 hreg = *(const float4*)(h_init + (size_t)(batch0 + hr) * SD + s0 + hc);

    const int ct1 = hc >> 4;
    const int rg1 = hr & 3;
    const int ln1 = (hr >> 2) * 16 + (hc & 15);

    const int er  = tid >> 4;           // err element (row, col): one per thread
    const int ec  = tid & 15;
    const int rg2 = er & 3;
    const int ln2 = (er >> 2) * 16 + ec;
    const float bo = b_o[o0 + ec];

    const size_t t_off = (size_t)(batch0 + hr) * SD + s0 + hc;

    // ---- one-time XCD placement check (agent-scope, always correct) ----
    unsigned xcc = 0;
    asm volatile("s_getreg_b32 %0, hwreg(HW_REG_XCC_ID)" : "=s"(xcc));
    if (tid == 0)
        __hip_atomic_store(xarr + wi, xcc + 1u, __ATOMIC_RELAXED, __HIP_MEMORY_SCOPE_AGENT);
    __syncthreads();   // drains the xcc store (vmcnt) before the arrival add
    if (tid == 0) {
        unsigned old = __hip_atomic_fetch_add(scnt, 1u, __ATOMIC_RELAXED, __HIP_MEMORY_SCOPE_AGENT);
        if (old == 15u)
            __hip_atomic_store(sflag, 1u, __ATOMIC_RELAXED, __HIP_MEMORY_SCOPE_AGENT);
        while (__hip_atomic_load(sflag, __ATOMIC_RELAXED, __HIP_MEMORY_SCOPE_AGENT) < 1u)
            __builtin_amdgcn_s_sleep(1);
    }
    __syncthreads();
    if (tid < 16)
        sx[tid] = __hip_atomic_load(xarr + tid, __ATOMIC_RELAXED, __HIP_MEMORY_SCOPE_AGENT);
    __syncthreads();
    bool fastpath = true;
    for (int j = 1; j < 16; ++j) fastpath &= (sx[j] == sx[0]);

    // ---- barrier primitives: agent scope, placement-independent ----
    // publish: drain all waves' t-stores (syncthreads emits vmcnt(0)), then
    // one agent flag store. No RMW hop, no last-arriver serialization.
    auto publish = [&](unsigned val) {
        __syncthreads();
        if (tid == 0)
            __hip_atomic_store(myflag, val, __ATOMIC_RELAXED, __HIP_MEMORY_SCOPE_AGENT);
    };
    // wait: single throttled poller per WG; 16 agent loads pipeline to ~one
    // latency. Throttle = round-0-proven s_sleep(1) cadence.
    auto wait_all = [&](unsigned target) {
        if (tid == 0) {
            for (;;) {
                unsigned mn = 0xFFFFFFFFu;
#pragma unroll
                for (int j = 0; j < 16; ++j) {
                    unsigned v = __hip_atomic_load(flags + j, __ATOMIC_RELAXED, __HIP_MEMORY_SCOPE_AGENT);
                    mn = v < mn ? v : mn;
                }
                if (mn >= target) break;
                __builtin_amdgcn_s_sleep(1);
            }
        }
        __syncthreads();
    };

    // ================= main body, data path specialized on FAST =================
    auto body = [&](auto FC) {
        constexpr bool FAST = decltype(FC)::value;

        auto t_store = [&](unsigned short* p, float a, float b, float c, float d) {
            unsigned long long v = (unsigned long long)f2bf(a)
                                 | ((unsigned long long)f2bf(b) << 16)
                                 | ((unsigned long long)f2bf(c) << 32)
                                 | ((unsigned long long)f2bf(d) << 48);
            if constexpr (FAST) {             // write-through L1 -> lands in XCD L2 (r6-verified)
                *(unsigned long long*)p = v;
            } else {
                __hip_atomic_store((unsigned long long*)p, v, __ATOMIC_RELAXED, __HIP_MEMORY_SCOPE_AGENT);
            }
        };

        // load 8 A fragments; FAST: sc0 loads serve from XCD L2 (r6-verified;
        // correctness additionally rests on t-lines being cold in L1 --
        // 32KB/step streams through the 32KB L1, lines cannot survive the
        // 3-step buffer cycle).
        auto loadA = [&](bf8 (&A)[8], const unsigned short* ap) {
            if constexpr (FAST) {
                u32x4 r[8];
#pragma unroll
                for (int kk = 0; kk < 8; ++kk)
                    asm volatile("global_load_dwordx4 %0, %1, off sc0"
                                 : "=v"(r[kk]) : "v"((const void*)(ap + kk * 32)));
                asm volatile("s_waitcnt vmcnt(0)" ::: "memory");
                __builtin_amdgcn_sched_barrier(0);   // rule #18: keep MFMAs after the wait
#pragma unroll
                for (int kk = 0; kk < 8; ++kk) {
                    BF16x8 u; u.u = r[kk]; A[kk] = u.v;
                }
            } else {
#pragma unroll
                for (int kk = 0; kk < 8; ++kk) A[kk] = t_load16_agent(ap + kk * 32);
            }
        };

        bf8 A[8];  // A fragments of current t tile (reused by gemm1 AND gemm2)

        auto gemm2 = [&](int tstep) {
            size_t oidx = (size_t)tstep * (BATCH * OD) + (size_t)(batch0 + er) * OD + o0 + ec;
            float xv = x[oidx];                       // issue early, overlaps MFMA
            f32x4 c = {0.f, 0.f, 0.f, 0.f};
#pragma unroll
            for (int kk = 0; kk < 8; ++kk)
                c = __builtin_amdgcn_mfma_f32_16x16x32_bf16(A[kk], B2[kk], c, 0, 0, 0);
#pragma unroll
            for (int q = 0; q < 4; ++q) red2[wid][q][lane] = c[q];
            __syncthreads();
            float sum = red2[0][rg2][ln2] + red2[1][rg2][ln2]
                      + red2[2][rg2][ln2] + red2[3][rg2][ln2];
            out[oidx] = sum + bo - xv;
        };

        // ---- t0 = tanh(h_init) into buffer 0 ----
        t_store(tbase + t_off, fast_tanh(hreg.x), fast_tanh(hreg.y),
                               fast_tanh(hreg.z), fast_tanh(hreg.w));
        publish(1u);
        wait_all(1u);

        for (int i = 0; i < SEQ; ++i) {
            const unsigned short* tb = tbase + (size_t)(i % 3) * (BATCH * SD);
            unsigned short* tn = tbase + (size_t)((i + 1) % 3) * (BATCH * SD);

            // ---- A fragments: 16 rows x wave's K slice ----
            const unsigned short* ap = tb + (size_t)(batch0 + l15) * SD + k0 + lq * 8;
            loadA(A, ap);

            // ---- recurrent GEMM: C[16x64] per wave over its K slice ----
            f32x4 acc0 = {0.f,0.f,0.f,0.f}, acc1 = {0.f,0.f,0.f,0.f};
            f32x4 acc2 = {0.f,0.f,0.f,0.f}, acc3 = {0.f,0.f,0.f,0.f};
#pragma unroll
            for (int kk = 0; kk < 8; ++kk) {
                acc0 = __builtin_amdgcn_mfma_f32_16x16x32_bf16(A[kk], B1[0][kk], acc0, 0, 0, 0);
                acc1 = __builtin_amdgcn_mfma_f32_16x16x32_bf16(A[kk], B1[1][kk], acc1, 0, 0, 0);
                acc2 = __builtin_amdgcn_mfma_f32_16x16x32_bf16(A[kk], B1[2][kk], acc2, 0, 0, 0);
                acc3 = __builtin_amdgcn_mfma_f32_16x16x32_bf16(A[kk], B1[3][kk], acc3, 0, 0, 0);
            }
#pragma unroll
            for (int q = 0; q < 4; ++q) {
                red1[wid][0][q][lane] = acc0[q];
                red1[wid][1][q][lane] = acc1[q];
                red1[wid][2][q][lane] = acc2[q];
                red1[wid][3][q][lane] = acc3[q];
            }
            __syncthreads();

            // ---- K-reduction across 4 waves + leaky h update + tanh + publish ----
            float4 p0 = *(const float4*)&red1[0][ct1][rg1][ln1];
            float4 p1 = *(const float4*)&red1[1][ct1][rg1][ln1];
            float4 p2 = *(const float4*)&red1[2][ct1][rg1][ln1];
            float4 p3 = *(const float4*)&red1[3][ct1][rg1][ln1];
            hreg.x = 0.9f * hreg.x + 0.1f * (p0.x + p1.x + p2.x + p3.x + br4.x);
            hreg.y = 0.9f * hreg.y + 0.1f * (p0.y + p1.y + p2.y + p3.y + br4.y);
            hreg.z = 0.9f * hreg.z + 0.1f * (p0.z + p1.z + p2.z + p3.z + br4.z);
            hreg.w = 0.9f * hreg.w + 0.1f * (p0.w + p1.w + p2.w + p3.w + br4.w);
            t_store(tn + t_off, fast_tanh(hreg.x), fast_tanh(hreg.y),
                                fast_tanh(hreg.z), fast_tanh(hreg.w));

            publish((unsigned)(i + 2));   // drain + one agent flag store

            // ---- off-critical-path: err_{i-1} reuses this step's A frags ----
            if (i >= 1) gemm2(i - 1);

            wait_all((unsigned)(i + 2));  // t_{i+1} available from all 16 producers
        }

        // ---- epilogue: err_{511} from t_512 (published; last wait ordered it) ----
        {
            const unsigned short* tb = tbase + (size_t)(SEQ % 3) * (BATCH * SD);
            const unsigned short* ap = tb + (size_t)(batch0 + l15) * SD + k0 + lq * 8;
            loadA(A, ap);
            gemm2(SEQ - 1);
        }
    };

    if (fastpath) {
        body(BoolC<true>{});
    } else {
        body(BoolC<false>{});
    }
}

extern "C" void kernel_launch(void* const* d_in, const int* in_sizes, int n_in,
                              void* d_out, int out_size, void* d_ws, size_t ws_size,
                              hipStream_t stream)
{
    const float* x      = (const float*)d_in[0];
    const float* h_init = (const float*)d_in[1];
    const float* w_r    = (const float*)d_in[2];
    const float* b_r    = (const float*)d_in[3];
    const float* w_o    = (const float*)d_in[4];
    const float* b_o    = (const float*)d_in[5];
    float* out = (float*)d_out;

    // ws layout: [0,4096) per-group control blocks (256B each), [4096, +3*512K) t triple buffer
    hipMemsetAsync(d_ws, 0, 4096, stream);
    rnn_persistent<<<dim3(256), dim3(256), 0, stream>>>(
        x, h_init, w_r, b_r, w_o, b_o, out, (unsigned char*)d_ws);
}